// Round 1
// baseline (91.869 us; speedup 1.0000x reference)
//
#include <hip/hip_runtime.h>

// PatchDivider: reorder pts by serialization order, split into 64-point
// patches, subtract per-patch mean. One 64-lane wave == one patch.
//
// B=32, N=131072, PATCH=64, L=2048 -> 65536 patches.
// d_in[0]: pts    float32 [B*N*3]  = 12,582,912 floats
// d_in[1]: orders int32   [B*N]    =  4,194,304 ints (jnp int64 folds to i32)
// d_out  : patches [B,L,64,3] then centers [B,L,3], float32, concatenated.

#define PD_B 32
#define PD_N 131072
#define PD_PATCH 64
#define PD_L (PD_N / PD_PATCH)          // 2048
#define PD_NPATCH (PD_B * PD_L)         // 65536

__global__ __launch_bounds__(256) void PatchDivider_57621281243393_kernel(
    const float* __restrict__ pts,
    const int* __restrict__ orders,
    float* __restrict__ out)
{
    // one wave (64 lanes) per patch; lane i owns point i of the patch
    const int gtid = blockIdx.x * blockDim.x + threadIdx.x;
    const int wave = gtid >> 6;           // patch index in [0, 65536)
    const int lane = threadIdx.x & 63;
    if (wave >= PD_NPATCH) return;

    const long long point = (long long)wave * PD_PATCH + lane;
    const int idx = orders[point];        // coalesced 4B/lane

    // gather: 3 floats at random location (L3 absorbs line overfetch)
    const float* __restrict__ p = pts + (long long)idx * 3;
    const float x = p[0];
    const float y = p[1];
    const float z = p[2];

    // wave-wide sum across all 64 lanes (butterfly)
    float sx = x, sy = y, sz = z;
    #pragma unroll
    for (int off = 32; off >= 1; off >>= 1) {
        sx += __shfl_xor(sx, off, 64);
        sy += __shfl_xor(sy, off, 64);
        sz += __shfl_xor(sz, off, 64);
    }
    const float inv = 1.0f / (float)PD_PATCH;
    const float cx = sx * inv;
    const float cy = sy * inv;
    const float cz = sz * inv;

    // centered point -> patches output (wave writes contiguous 768B span)
    float* __restrict__ po = out + point * 3;
    po[0] = x - cx;
    po[1] = y - cy;
    po[2] = z - cz;

    // lane 0 writes the patch center after the patches block
    if (lane == 0) {
        float* __restrict__ co =
            out + (long long)PD_NPATCH * PD_PATCH * 3 + (long long)wave * 3;
        co[0] = cx;
        co[1] = cy;
        co[2] = cz;
    }
}

extern "C" void kernel_launch(void* const* d_in, const int* in_sizes, int n_in,
                              void* d_out, int out_size, void* d_ws, size_t ws_size,
                              hipStream_t stream) {
    const float* pts   = (const float*)d_in[0];
    const int* orders  = (const int*)d_in[1];
    float* out         = (float*)d_out;

    const int total_threads = PD_NPATCH * PD_PATCH;   // 4,194,304
    const int block = 256;
    const int grid = total_threads / block;           // 16,384

    PatchDivider_57621281243393_kernel<<<grid, block, 0, stream>>>(pts, orders, out);
}